// Round 2
// baseline (745.488 us; speedup 1.0000x reference)
//
#include <hip/hip_runtime.h>
#include <hip/hip_bf16.h>
#include <stdint.h>

#define B_ 256
#define S_ 256
#define D_ 1024
#define P_ 512
#define SH 254            /* S-2 */
#define M_ (B_*SH)        /* 65024 */
#define EPSF 1e-7f

typedef __attribute__((ext_vector_type(8))) short short8v;
typedef __attribute__((ext_vector_type(4))) float float4v;

__device__ inline short f2bf(float f) {
  __hip_bfloat16 h = __float2bfloat16(f);
  return *reinterpret_cast<short*>(&h);
}
__device__ inline float fast_tanh(float x) {
  float e = __expf(2.0f * x);
  return 1.0f - 2.0f * __builtin_amdgcn_rcpf(e + 1.0f);
}

// ---------------- mask dtype detection ----------------
// flag: 0 = int32 mask, 1 = byte (bool) mask, 2 = float32 mask
__global__ void k_detect(const unsigned char* m, int* flag) {
  __shared__ int c0, c3;
  if (threadIdx.x == 0) { c0 = 0; c3 = 0; }
  __syncthreads();
  int f0 = 0, f3 = 0;
  for (int i = threadIdx.x; i < 4096; i += 256) {
    unsigned char v = m[i];
    if (v != 0) {
      if ((i & 3) == 0) f0 = 1;
      if ((i & 3) == 3) f3 = 1;
    }
  }
  if (f0) atomicOr(&c0, 1);
  if (f3) atomicOr(&c3, 1);
  __syncthreads();
  if (threadIdx.x == 0) {
    int f;
    if (c3 == 0) f = 0;
    else if (c0 != 0) f = 1;
    else f = 2;
    *flag = f;
  }
}

// proj_head (D x P) -> chunked transposed bf16: out[kc*(P*32) + n*32 + kr]
__global__ void k_trans_head(const float* w, short* out) {
  int idx = blockIdx.x * 256 + threadIdx.x;   // D_*P_ threads
  int n = idx & (P_ - 1);
  int k = idx >> 9;
  out[(k >> 5) * (P_*32) + n*32 + (k & 31)] = f2bf(w[k*P_ + n]);
}

// hidden (2 x P x P) -> two chunked transposed bf16 arrays
__global__ void k_trans_hidden(const float* h, short* o0, short* o1) {
  int idx = blockIdx.x * 256 + threadIdx.x;   // 2*P_*P_ threads
  int which = idx >> 18;
  int j = idx & ((P_*P_) - 1);
  int n = j & (P_ - 1);
  int k = j >> 9;
  short v = f2bf(h[which*(P_*P_) + k*P_ + n]);
  short* o = which ? o1 : o0;
  o[(k >> 5) * (P_*32) + n*32 + (k & 31)] = v;
}

// pc[b][p] = x[b,254,:]@proj_prep[:,p] + x[b,255,:]@proj_child[:,p]
// grid: 256 blocks = 16 batch-groups x 16 col-strips; block = 16 batches x 32 cols
__global__ void __launch_bounds__(512) k_pc(const float* __restrict__ x,
                                            const float* __restrict__ wp,
                                            const float* __restrict__ wc,
                                            float* __restrict__ pc) {
  __shared__ float xs[16][256];
  int bg = blockIdx.x >> 4, cs = blockIdx.x & 15;
  int t = threadIdx.x;
  int bloc = t >> 5, c = t & 31;
  int batch = bg * 16 + bloc;
  int col = cs * 32 + c;
  float acc = 0.f;
  #pragma unroll
  for (int half = 0; half < 2; half++) {
    const float* wsrc = half ? wc : wp;
    for (int kc = 0; kc < 4; kc++) {
      // stage xs[bloc][0..255] = x[batch, 254+half, kc*256 .. +255]
      const float* xr = x + ((size_t)(batch * S_ + SH + half)) * D_ + kc*256 + c*8;
      float4 v0 = *(const float4*)(xr + 0);
      float4 v1 = *(const float4*)(xr + 4);
      __syncthreads();
      *(float4*)&xs[bloc][c*8 + 0] = v0;
      *(float4*)&xs[bloc][c*8 + 4] = v1;
      __syncthreads();
      const float* wv = wsrc + (size_t)(kc*256) * P_ + col;
      #pragma unroll 8
      for (int d = 0; d < 256; d++) {
        acc += xs[bloc][d] * wv[(size_t)d * P_];
      }
    }
  }
  pc[batch * P_ + col] = acc;
}

// ---------------- fused 3-GEMM main kernel ----------------
// block: 512 threads = 8 waves (1m x 8n); 64 rows x 512 cols per block.
// B operands read DIRECTLY from global (L2-resident chunked weights) — no Bs,
// no per-chunk barriers. A double-buffered in LDS in BK=128 super-chunks.
__global__ void __launch_bounds__(512, 2) k_main(
    const float* __restrict__ x, const short* __restrict__ wth,
    const short* __restrict__ h0t, const short* __restrict__ h1t,
    const float* __restrict__ scorer, const float* __restrict__ pc,
    float* __restrict__ scores)
{
  __shared__ __attribute__((aligned(16))) short As[2][64*136];  // 34816 B, 2-way free
  __shared__ __attribute__((aligned(16))) short Cs[64*520];     // 66560 B, 2-way free
  __shared__ float scorer_s[P_];
  __shared__ float score_s[64];

  const int tid  = threadIdx.x;
  const int lane = tid & 63;
  const int wn   = tid >> 6;            // wave = column strip wn*64
  const int l15  = lane & 15, quad = lane >> 4;
  const int rowbase = blockIdx.x * 64;

  scorer_s[tid] = scorer[tid];
  if (tid < 64) score_s[tid] = 0.f;

  // A staging map: thread -> (row = tid>>3, 16 consecutive k at (tid&7)*16)
  const int arow = tid >> 3;
  const int akg  = (tid & 7) * 16;
  {
    int r0 = rowbase + arow;
    int ab = r0 / SH;
    int as_ = r0 - ab * SH;
    const float* aptr = x + ((size_t)(ab * S_ + as_)) * D_ + akg;

    // preload super-chunk 0
    float4 st0 = *(const float4*)(aptr + 0);
    float4 st1 = *(const float4*)(aptr + 4);
    float4 st2 = *(const float4*)(aptr + 8);
    float4 st3 = *(const float4*)(aptr + 12);
    short8v s0 = { f2bf(st0.x),f2bf(st0.y),f2bf(st0.z),f2bf(st0.w),
                   f2bf(st1.x),f2bf(st1.y),f2bf(st1.z),f2bf(st1.w) };
    short8v s1 = { f2bf(st2.x),f2bf(st2.y),f2bf(st2.z),f2bf(st2.w),
                   f2bf(st3.x),f2bf(st3.y),f2bf(st3.z),f2bf(st3.w) };
    *(short8v*)&As[0][arow*136 + akg]     = s0;
    *(short8v*)&As[0][arow*136 + akg + 8] = s1;
    __syncthreads();

    float4v acc[4][4];
    #pragma unroll
    for (int i = 0; i < 4; i++)
      #pragma unroll
      for (int j = 0; j < 4; j++) acc[i][j] = (float4v){0.f,0.f,0.f,0.f};

    const uint4* wb = (const uint4*)wth;

    // ---- Stage 1: K=1024, 8 super-chunks of 128, dbuf, 1 barrier each ----
    for (int sc = 0; sc < 8; sc++) {
      const int cur = sc & 1;
      float4 n0, n1, n2, n3;
      if (sc < 7) {
        const float* p = aptr + (sc + 1) * 128;
        n0 = *(const float4*)(p + 0);
        n1 = *(const float4*)(p + 4);
        n2 = *(const float4*)(p + 8);
        n3 = *(const float4*)(p + 12);
      }
      #pragma unroll
      for (int c = 0; c < 4; c++) {
        const int kc = sc * 4 + c;
        short8v a[4];
        #pragma unroll
        for (int mt = 0; mt < 4; mt++)
          a[mt] = *(const short8v*)&As[cur][(mt*16 + l15)*136 + c*32 + quad*8];
        #pragma unroll
        for (int nt = 0; nt < 4; nt++) {
          uint4 bv = wb[(size_t)kc*2048 + (wn*64 + nt*16 + l15)*4 + quad];
          short8v bfr = *(short8v*)&bv;
          #pragma unroll
          for (int mt = 0; mt < 4; mt++)
            acc[mt][nt] = __builtin_amdgcn_mfma_f32_16x16x32_bf16(a[mt], bfr, acc[mt][nt], 0, 0, 0);
        }
      }
      if (sc < 7) {
        short8v w0 = { f2bf(n0.x),f2bf(n0.y),f2bf(n0.z),f2bf(n0.w),
                       f2bf(n1.x),f2bf(n1.y),f2bf(n1.z),f2bf(n1.w) };
        short8v w1 = { f2bf(n2.x),f2bf(n2.y),f2bf(n2.z),f2bf(n2.w),
                       f2bf(n3.x),f2bf(n3.y),f2bf(n3.z),f2bf(n3.w) };
        *(short8v*)&As[cur ^ 1][arow*136 + akg]     = w0;
        *(short8v*)&As[cur ^ 1][arow*136 + akg + 8] = w1;
      }
      __syncthreads();
    }

    // epilogue 1: + pc bias, tanh, -> Cs (bf16, paired b32 writes)
    #pragma unroll
    for (int mt = 0; mt < 4; mt++) {
      #pragma unroll
      for (int j = 0; j < 4; j++) {
        int rl = mt*16 + quad*4 + j;
        int rg = rowbase + rl;
        int bb = rg / SH;
        const float* pcb = pc + bb * P_;
        #pragma unroll
        for (int nt = 0; nt < 4; nt++) {
          int col = wn*64 + nt*16 + l15;
          float v = fast_tanh(acc[mt][nt][j] + pcb[col]);
          float o = __shfl_xor(v, 1, 64);
          unsigned hs = (unsigned short)f2bf(v);
          unsigned ho = (unsigned short)f2bf(o);
          if ((l15 & 1) == 0)
            *(unsigned*)&Cs[rl*520 + col] = hs | (ho << 16);
        }
      }
    }
    __syncthreads();

    // ---- Stages 2 & 3: K=512, A from Cs, B from global, NO inner barriers ----
    #pragma unroll 1
    for (int stage = 0; stage < 2; stage++) {
      const uint4* hb = (const uint4*)(stage ? h1t : h0t);
      #pragma unroll
      for (int i = 0; i < 4; i++)
        #pragma unroll
        for (int j = 0; j < 4; j++) acc[i][j] = (float4v){0.f,0.f,0.f,0.f};
      #pragma unroll 4
      for (int kc = 0; kc < 16; kc++) {
        short8v a[4];
        #pragma unroll
        for (int mt = 0; mt < 4; mt++)
          a[mt] = *(const short8v*)&Cs[(mt*16 + l15)*520 + kc*32 + quad*8];
        #pragma unroll
        for (int nt = 0; nt < 4; nt++) {
          uint4 bv = hb[(size_t)kc*2048 + (wn*64 + nt*16 + l15)*4 + quad];
          short8v bfr = *(short8v*)&bv;
          #pragma unroll
          for (int mt = 0; mt < 4; mt++)
            acc[mt][nt] = __builtin_amdgcn_mfma_f32_16x16x32_bf16(a[mt], bfr, acc[mt][nt], 0, 0, 0);
        }
      }
      if (stage == 0) {
        __syncthreads();   // all Cs reads done before overwrite
        #pragma unroll
        for (int mt = 0; mt < 4; mt++) {
          #pragma unroll
          for (int j = 0; j < 4; j++) {
            int rl = mt*16 + quad*4 + j;
            #pragma unroll
            for (int nt = 0; nt < 4; nt++) {
              int col = wn*64 + nt*16 + l15;
              float v = fast_tanh(acc[mt][nt][j]);
              float o = __shfl_xor(v, 1, 64);
              unsigned hs = (unsigned short)f2bf(v);
              unsigned ho = (unsigned short)f2bf(o);
              if ((l15 & 1) == 0)
                *(unsigned*)&Cs[rl*520 + col] = hs | (ho << 16);
            }
          }
        }
        __syncthreads();
      }
    }

    // ---- epilogue 3: tanh, scorer dot, exp ----
    #pragma unroll
    for (int mt = 0; mt < 4; mt++) {
      #pragma unroll
      for (int j = 0; j < 4; j++) {
        float part = 0.f;
        #pragma unroll
        for (int nt = 0; nt < 4; nt++) {
          int col = wn*64 + nt*16 + l15;
          part += fast_tanh(acc[mt][nt][j]) * scorer_s[col];
        }
        #pragma unroll
        for (int o = 1; o < 16; o <<= 1) part += __shfl_xor(part, o, 64);
        if (l15 == 0) atomicAdd(&score_s[mt*16 + quad*4 + j], part);
      }
    }
  }
  __syncthreads();
  if (tid < 64) scores[rowbase + tid] = __expf(score_s[tid]);
}

// ---------------- masked softmax ----------------
__global__ void __launch_bounds__(256) k_softmax(const float* __restrict__ scores,
                                                 const void* __restrict__ mask,
                                                 const int* __restrict__ flag,
                                                 float* __restrict__ out) {
  int b = blockIdx.x, t = threadIdx.x;
  int lane = t & 63, w = t >> 6;
  __shared__ float ps[4];
  float me = 0.f;
  bool valid = t < SH;
  if (valid) {
    float e = scores[b*SH + t];
    int f = *flag;
    bool mb;
    if (f == 1)      mb = ((const unsigned char*)mask)[b*S_ + t] != 0;
    else if (f == 2) mb = ((const float*)mask)[b*S_ + t] != 0.0f;
    else             mb = ((const int*)mask)[b*S_ + t] != 0;
    me = mb ? e : 0.f;
  }
  float v = me;
  for (int o = 1; o < 64; o <<= 1) v += __shfl_xor(v, o, 64);
  if (lane == 0) ps[w] = v;
  __syncthreads();
  float tot = ps[0] + ps[1] + ps[2] + ps[3] + EPSF;
  if (valid) out[b*SH + t] = me / tot;
}

extern "C" void kernel_launch(void* const* d_in, const int* in_sizes, int n_in,
                              void* d_out, int out_size, void* d_ws, size_t ws_size,
                              hipStream_t stream) {
  const float* x          = (const float*)d_in[0];
  const float* proj_head  = (const float*)d_in[1];
  const float* proj_prep  = (const float*)d_in[2];
  const float* proj_child = (const float*)d_in[3];
  const float* hidden     = (const float*)d_in[4];
  const float* scorer     = (const float*)d_in[5];
  const void*  mask       = d_in[6];
  float* out = (float*)d_out;
  char* ws = (char*)d_ws;

  // ws layout (256B-aligned offsets)
  int*   flag   = (int*)  (ws + 0);
  float* pc     = (float*)(ws + 256);        // 256*512*4   = 524288
  short* wth    = (short*)(ws + 524544);     // 512*1024*2  = 1048576
  short* h0t    = (short*)(ws + 1573120);    // 512*512*2   = 524288
  short* h1t    = (short*)(ws + 2097408);    // 512*512*2   = 524288
  float* scores = (float*)(ws + 2621696);    // 65024*4     = 260096

  k_detect<<<1, 256, 0, stream>>>((const unsigned char*)mask, flag);
  k_trans_head<<<2048, 256, 0, stream>>>(proj_head, wth);
  k_trans_hidden<<<2048, 256, 0, stream>>>(hidden, h0t, h1t);
  k_pc<<<256, 512, 0, stream>>>(x, proj_prep, proj_child, pc);
  k_main<<<1016, 512, 0, stream>>>(x, wth, h0t, h1t, scorer, pc, scores);
  k_softmax<<<256, 256, 0, stream>>>(scores, mask, flag, out);
}

// Round 3
// 695.251 us; speedup vs baseline: 1.0723x; 1.0723x over previous
//
#include <hip/hip_runtime.h>
#include <hip/hip_bf16.h>
#include <stdint.h>

#define B_ 256
#define S_ 256
#define D_ 1024
#define P_ 512
#define SH 254            /* S-2 */
#define M_ (B_*SH)        /* 65024 */
#define EPSF 1e-7f

typedef __attribute__((ext_vector_type(8))) short short8v;
typedef __attribute__((ext_vector_type(4))) float float4v;

__device__ inline short f2bf(float f) {
  __hip_bfloat16 h = __float2bfloat16(f);
  return *reinterpret_cast<short*>(&h);
}
__device__ inline float fast_tanh(float x) {
  float e = __expf(2.0f * x);
  return 1.0f - 2.0f * __builtin_amdgcn_rcpf(e + 1.0f);
}

// ---------------- mask dtype detection ----------------
__global__ void k_detect(const unsigned char* m, int* flag) {
  __shared__ int c0, c3;
  if (threadIdx.x == 0) { c0 = 0; c3 = 0; }
  __syncthreads();
  int f0 = 0, f3 = 0;
  for (int i = threadIdx.x; i < 4096; i += 256) {
    unsigned char v = m[i];
    if (v != 0) {
      if ((i & 3) == 0) f0 = 1;
      if ((i & 3) == 3) f3 = 1;
    }
  }
  if (f0) atomicOr(&c0, 1);
  if (f3) atomicOr(&c3, 1);
  __syncthreads();
  if (threadIdx.x == 0) {
    int f;
    if (c3 == 0) f = 0;
    else if (c0 != 0) f = 1;
    else f = 2;
    *flag = f;
  }
}

// proj_head (D x P) -> chunked transposed bf16: out[kc*(P*32) + n*32 + kr]
// pair-packed writes (one b32 per thread)
__global__ void k_trans_head(const float* __restrict__ w, short* __restrict__ out) {
  int idx = blockIdx.x * 256 + threadIdx.x;   // 262144 threads
  int kc  = idx >> 13;          // 0..31
  int j   = idx & 8191;
  int krp = j >> 9;             // 0..15
  int n   = j & 511;
  int k0  = kc * 32 + krp * 2;
  unsigned lo = (unsigned short)f2bf(w[(size_t)k0 * P_ + n]);
  unsigned hi = (unsigned short)f2bf(w[(size_t)(k0 + 1) * P_ + n]);
  ((unsigned*)out)[kc * 8192 + n * 16 + krp] = lo | (hi << 16);
}

// hidden (2 x P x P) -> two chunked transposed bf16 arrays, pair-packed
__global__ void k_trans_hidden(const float* __restrict__ h,
                               short* __restrict__ o0, short* __restrict__ o1) {
  int idx = blockIdx.x * 256 + threadIdx.x;   // 262144 threads
  int which = idx >> 17;
  int j = idx & 131071;
  int kc  = j >> 13;            // 0..15
  int r   = j & 8191;
  int krp = r >> 9;
  int n   = r & 511;
  const float* hs = h + (size_t)which * (P_*P_);
  int k0 = kc * 32 + krp * 2;
  unsigned lo = (unsigned short)f2bf(hs[(size_t)k0 * P_ + n]);
  unsigned hi = (unsigned short)f2bf(hs[(size_t)(k0 + 1) * P_ + n]);
  unsigned* o = (unsigned*)(which ? o1 : o0);
  o[kc * 8192 + n * 16 + krp] = lo | (hi << 16);
}

// pc[b][p] = x[b,254,:]@proj_prep[:,p] + x[b,255,:]@proj_child[:,p]
__global__ void __launch_bounds__(512) k_pc(const float* __restrict__ x,
                                            const float* __restrict__ wp,
                                            const float* __restrict__ wc,
                                            float* __restrict__ pc) {
  __shared__ float xs[16][256];
  int bg = blockIdx.x >> 4, cs = blockIdx.x & 15;
  int t = threadIdx.x;
  int bloc = t >> 5, c = t & 31;
  int batch = bg * 16 + bloc;
  int col = cs * 32 + c;
  float acc = 0.f;
  #pragma unroll
  for (int half = 0; half < 2; half++) {
    const float* wsrc = half ? wc : wp;
    for (int kc = 0; kc < 4; kc++) {
      const float* xr = x + ((size_t)(batch * S_ + SH + half)) * D_ + kc*256 + c*8;
      float4 v0 = *(const float4*)(xr + 0);
      float4 v1 = *(const float4*)(xr + 4);
      __syncthreads();
      *(float4*)&xs[bloc][c*8 + 0] = v0;
      *(float4*)&xs[bloc][c*8 + 4] = v1;
      __syncthreads();
      const float* wv = wsrc + (size_t)(kc*256) * P_ + col;
      #pragma unroll 8
      for (int d = 0; d < 256; d++) {
        acc += xs[bloc][d] * wv[(size_t)d * P_];
      }
    }
  }
  pc[batch * P_ + col] = acc;
}

// ---------------- fused 3-GEMM main kernel ----------------
// 512 threads = 8 waves (1m x 8n); 64 rows x 512 cols per block.
// B read directly from global (L2-resident) with explicit register
// double-buffering, prefetch distance = 1 kc-pair (~32 MFMA of cover).
// A double-buffered in LDS (BK=128). Cs (composed) stays in LDS.

// load one kc-pair (8 B fragments) into a register buffer
#define LB2(DST, BASE, KC0) do {                                    \
  const uint4* _p = (BASE) + (size_t)(KC0)*2048 + bcol;             \
  DST[0]=_p[0];    DST[1]=_p[64];      DST[2]=_p[128];  DST[3]=_p[192]; \
  DST[4]=_p[2048]; DST[5]=_p[2048+64]; DST[6]=_p[2048+128]; DST[7]=_p[2048+192]; \
} while(0)

// stage-1 MFMA on a kc-pair, A from As[CUR] at chunk offsets CB, CB+1
#define APAIR(CUR, CB, BUF) do {                                    \
  _Pragma("unroll") for (int cc = 0; cc < 2; cc++) {                \
    short8v a_[4];                                                  \
    _Pragma("unroll") for (int mt = 0; mt < 4; mt++)                \
      a_[mt] = *(const short8v*)&As[CUR][(mt*16 + l15)*136 + ((CB)+cc)*32 + quad*8]; \
    _Pragma("unroll") for (int nt = 0; nt < 4; nt++) {              \
      short8v bfr = *(short8v*)&BUF[cc*4 + nt];                     \
      _Pragma("unroll") for (int mt = 0; mt < 4; mt++)              \
        acc[mt][nt] = __builtin_amdgcn_mfma_f32_16x16x32_bf16(a_[mt], bfr, acc[mt][nt], 0, 0, 0); \
    }                                                               \
  }                                                                 \
} while(0)

// stage-2/3 pair: prefetch next pair into NXTB, MFMA current from Cs
#define S23(P, CURB, NXTB) do {                                     \
  if ((P) < 7) { LB2(NXTB, hb, 2*(P)+2); }                          \
  else if (stage == 0) { LB2(NXTB, h1v, 0); }                       \
  _Pragma("unroll") for (int cc = 0; cc < 2; cc++) {                \
    short8v a_[4];                                                  \
    _Pragma("unroll") for (int mt = 0; mt < 4; mt++)                \
      a_[mt] = *(const short8v*)&Cs[(mt*16 + l15)*520 + (2*(P)+cc)*32 + quad*8]; \
    _Pragma("unroll") for (int nt = 0; nt < 4; nt++) {              \
      short8v bfr = *(short8v*)&CURB[cc*4 + nt];                    \
      _Pragma("unroll") for (int mt = 0; mt < 4; mt++)              \
        acc[mt][nt] = __builtin_amdgcn_mfma_f32_16x16x32_bf16(a_[mt], bfr, acc[mt][nt], 0, 0, 0); \
    }                                                               \
  }                                                                 \
} while(0)

__global__ void __launch_bounds__(512, 2) k_main(
    const float* __restrict__ x, const short* __restrict__ wth,
    const short* __restrict__ h0t, const short* __restrict__ h1t,
    const float* __restrict__ scorer, const float* __restrict__ pc,
    float* __restrict__ scores)
{
  __shared__ __attribute__((aligned(16))) short As[2][64*136];  // 34816 B
  __shared__ __attribute__((aligned(16))) short Cs[64*520];     // 66560 B
  __shared__ float scorer_s[P_];
  __shared__ float pcs[2][P_];
  __shared__ float score_ws[64][8];

  const int tid  = threadIdx.x;
  const int lane = tid & 63;
  const int wn   = tid >> 6;
  const int l15  = lane & 15, quad = lane >> 4;
  const int rowbase = blockIdx.x * 64;

  scorer_s[tid] = scorer[tid];
  const int bb0 = rowbase / SH;
  const int bb1 = (rowbase + 63) / SH;
  pcs[0][tid] = pc[bb0 * P_ + tid];
  pcs[1][tid] = pc[bb1 * P_ + tid];
  const int lim1 = (bb0 + 1) * SH;

  const int arow = tid >> 3;
  const int akg  = (tid & 7) * 16;
  int r0 = rowbase + arow;
  int ab = r0 / SH;
  int as_ = r0 - ab * SH;
  const float* aptr = x + ((size_t)(ab * S_ + as_)) * D_ + akg;

  const uint4* wbv = (const uint4*)wth;
  const uint4* h0v = (const uint4*)h0t;
  const uint4* h1v = (const uint4*)h1t;
  const int bcol = (wn*64 + l15)*4 + quad;

  uint4 bA[8], bB[8];

  // preload A super-chunk 0
  {
    float4 st0 = *(const float4*)(aptr + 0);
    float4 st1 = *(const float4*)(aptr + 4);
    float4 st2 = *(const float4*)(aptr + 8);
    float4 st3 = *(const float4*)(aptr + 12);
    short8v s0 = { f2bf(st0.x),f2bf(st0.y),f2bf(st0.z),f2bf(st0.w),
                   f2bf(st1.x),f2bf(st1.y),f2bf(st1.z),f2bf(st1.w) };
    short8v s1 = { f2bf(st2.x),f2bf(st2.y),f2bf(st2.z),f2bf(st2.w),
                   f2bf(st3.x),f2bf(st3.y),f2bf(st3.z),f2bf(st3.w) };
    *(short8v*)&As[0][arow*136 + akg]     = s0;
    *(short8v*)&As[0][arow*136 + akg + 8] = s1;
  }
  LB2(bA, wbv, 0);
  __syncthreads();

  float4v acc[4][4];
  #pragma unroll
  for (int i = 0; i < 4; i++)
    #pragma unroll
    for (int j = 0; j < 4; j++) acc[i][j] = (float4v){0.f,0.f,0.f,0.f};

  // ---- Stage 1: K=1024, 8 super-chunks of 128 ----
  for (int sc = 0; sc < 8; sc++) {
    const int cur = sc & 1;
    float4 n0, n1, n2, n3;
    if (sc < 7) {
      const float* p = aptr + (sc + 1) * 128;
      n0 = *(const float4*)(p + 0);
      n1 = *(const float4*)(p + 4);
      n2 = *(const float4*)(p + 8);
      n3 = *(const float4*)(p + 12);
    }
    LB2(bB, wbv, 4*sc + 2);
    APAIR(cur, 0, bA);
    if (sc < 7) { LB2(bA, wbv, 4*sc + 4); }
    APAIR(cur, 2, bB);
    if (sc < 7) {
      short8v w0 = { f2bf(n0.x),f2bf(n0.y),f2bf(n0.z),f2bf(n0.w),
                     f2bf(n1.x),f2bf(n1.y),f2bf(n1.z),f2bf(n1.w) };
      short8v w1 = { f2bf(n2.x),f2bf(n2.y),f2bf(n2.z),f2bf(n2.w),
                     f2bf(n3.x),f2bf(n3.y),f2bf(n3.z),f2bf(n3.w) };
      *(short8v*)&As[cur ^ 1][arow*136 + akg]     = w0;
      *(short8v*)&As[cur ^ 1][arow*136 + akg + 8] = w1;
    }
    __syncthreads();
  }

  // prefetch stage-2 first pair while doing epilogue 1
  LB2(bA, h0v, 0);

  // epilogue 1: + pc bias (from LDS), tanh, -> Cs
  #pragma unroll
  for (int mt = 0; mt < 4; mt++) {
    #pragma unroll
    for (int j = 0; j < 4; j++) {
      int rl = mt*16 + quad*4 + j;
      int rg = rowbase + rl;
      const float* pcb = (rg >= lim1) ? pcs[1] : pcs[0];
      #pragma unroll
      for (int nt = 0; nt < 4; nt++) {
        int col = wn*64 + nt*16 + l15;
        float v = fast_tanh(acc[mt][nt][j] + pcb[col]);
        float o = __shfl_xor(v, 1, 64);
        unsigned hs = (unsigned short)f2bf(v);
        unsigned ho = (unsigned short)f2bf(o);
        if ((l15 & 1) == 0)
          *(unsigned*)&Cs[rl*520 + col] = hs | (ho << 16);
      }
    }
  }
  __syncthreads();

  // ---- Stages 2 & 3: K=512, A from Cs, B prefetched in registers ----
  #pragma unroll 1
  for (int stage = 0; stage < 2; stage++) {
    const uint4* hb = stage ? h1v : h0v;
    #pragma unroll
    for (int i = 0; i < 4; i++)
      #pragma unroll
      for (int j = 0; j < 4; j++) acc[i][j] = (float4v){0.f,0.f,0.f,0.f};

    S23(0, bA, bB); S23(1, bB, bA);
    S23(2, bA, bB); S23(3, bB, bA);
    S23(4, bA, bB); S23(5, bB, bA);
    S23(6, bA, bB); S23(7, bB, bA);   // at stage 0 this prefetches h1 pair 0 into bA

    if (stage == 0) {
      __syncthreads();
      #pragma unroll
      for (int mt = 0; mt < 4; mt++) {
        #pragma unroll
        for (int j = 0; j < 4; j++) {
          int rl = mt*16 + quad*4 + j;
          #pragma unroll
          for (int nt = 0; nt < 4; nt++) {
            int col = wn*64 + nt*16 + l15;
            float v = fast_tanh(acc[mt][nt][j]);
            float o = __shfl_xor(v, 1, 64);
            unsigned hs = (unsigned short)f2bf(v);
            unsigned ho = (unsigned short)f2bf(o);
            if ((l15 & 1) == 0)
              *(unsigned*)&Cs[rl*520 + col] = hs | (ho << 16);
          }
        }
      }
      __syncthreads();
    }
  }

  // ---- epilogue 3: tanh, scorer dot, per-wave partials, exp ----
  #pragma unroll
  for (int mt = 0; mt < 4; mt++) {
    #pragma unroll
    for (int j = 0; j < 4; j++) {
      float part = 0.f;
      #pragma unroll
      for (int nt = 0; nt < 4; nt++) {
        int col = wn*64 + nt*16 + l15;
        part += fast_tanh(acc[mt][nt][j]) * scorer_s[col];
      }
      #pragma unroll
      for (int o = 1; o < 16; o <<= 1) part += __shfl_xor(part, o, 64);
      if (l15 == 0) score_ws[mt*16 + quad*4 + j][wn] = part;
    }
  }
  __syncthreads();
  if (tid < 64) {
    float s = 0.f;
    #pragma unroll
    for (int k = 0; k < 8; k++) s += score_ws[tid][k];
    scores[rowbase + tid] = __expf(s);
  }
}

// ---------------- masked softmax ----------------
__global__ void __launch_bounds__(256) k_softmax(const float* __restrict__ scores,
                                                 const void* __restrict__ mask,
                                                 const int* __restrict__ flag,
                                                 float* __restrict__ out) {
  int b = blockIdx.x, t = threadIdx.x;
  int lane = t & 63, w = t >> 6;
  __shared__ float ps[4];
  float me = 0.f;
  bool valid = t < SH;
  if (valid) {
    float e = scores[b*SH + t];
    int f = *flag;
    bool mb;
    if (f == 1)      mb = ((const unsigned char*)mask)[b*S_ + t] != 0;
    else if (f == 2) mb = ((const float*)mask)[b*S_ + t] != 0.0f;
    else             mb = ((const int*)mask)[b*S_ + t] != 0;
    me = mb ? e : 0.f;
  }
  float v = me;
  for (int o = 1; o < 64; o <<= 1) v += __shfl_xor(v, o, 64);
  if (lane == 0) ps[w] = v;
  __syncthreads();
  float tot = ps[0] + ps[1] + ps[2] + ps[3] + EPSF;
  if (valid) out[b*SH + t] = me / tot;
}

extern "C" void kernel_launch(void* const* d_in, const int* in_sizes, int n_in,
                              void* d_out, int out_size, void* d_ws, size_t ws_size,
                              hipStream_t stream) {
  const float* x          = (const float*)d_in[0];
  const float* proj_head  = (const float*)d_in[1];
  const float* proj_prep  = (const float*)d_in[2];
  const float* proj_child = (const float*)d_in[3];
  const float* hidden     = (const float*)d_in[4];
  const float* scorer     = (const float*)d_in[5];
  const void*  mask       = d_in[6];
  float* out = (float*)d_out;
  char* ws = (char*)d_ws;

  int*   flag   = (int*)  (ws + 0);
  float* pc     = (float*)(ws + 256);
  short* wth    = (short*)(ws + 524544);
  short* h0t    = (short*)(ws + 1573120);
  short* h1t    = (short*)(ws + 2097408);
  float* scores = (float*)(ws + 2621696);

  k_detect<<<1, 256, 0, stream>>>((const unsigned char*)mask, flag);
  k_trans_head<<<1024, 256, 0, stream>>>(proj_head, wth);
  k_trans_hidden<<<1024, 256, 0, stream>>>(hidden, h0t, h1t);
  k_pc<<<256, 512, 0, stream>>>(x, proj_prep, proj_child, pc);
  k_main<<<1016, 512, 0, stream>>>(x, wth, h0t, h1t, scorer, pc, scores);
  k_softmax<<<256, 256, 0, stream>>>(scores, mask, flag, out);
}